// Round 16
// baseline (203.422 us; speedup 1.0000x reference)
//
#include <hip/hip_runtime.h>

#define BB 4
#define NN 1024
#define DD 512
#define HH 8
#define DHH 64
#define FFF 2048

typedef __attribute__((ext_vector_type(8))) short bf16x8;
typedef __attribute__((ext_vector_type(4))) float f32x4;
typedef __attribute__((ext_vector_type(4))) unsigned short u16x4;

__device__ inline float wave_sum(float v) {
#pragma unroll
  for (int off = 32; off; off >>= 1) v += __shfl_xor(v, off);
  return v;
}

__device__ inline unsigned short cvt_bf16(float f) {
  union { float f; unsigned u; } x;
  x.f = f;
  unsigned r = x.u + 0x7FFFu + ((x.u >> 16) & 1u);
  return (unsigned short)(r >> 16);
}

__device__ __forceinline__ void gl_lds16(const void* g, void* l) {
  __builtin_amdgcn_global_load_lds(
      (__attribute__((address_space(1))) void*)(g),
      (__attribute__((address_space(3))) void*)(l), 16, 0, 0);
}

// ---------------- weight transpose + bf16 convert (all 6 weights, 1 launch) ----
__global__ __launch_bounds__(256) void wconv_kernel(
    const float* __restrict__ W0, const float* __restrict__ W1,
    const float* __restrict__ W2, const float* __restrict__ W3,
    const float* __restrict__ W4, const float* __restrict__ W5,
    unsigned short* __restrict__ out) {
  int bidx = blockIdx.x;
  const float* W; unsigned short* Wt; int K, N, local;
  if (bidx < 256) {
    int sel = bidx >> 6; local = bidx & 63;
    W = sel == 0 ? W0 : sel == 1 ? W1 : sel == 2 ? W2 : W3;
    K = 512; N = 512; Wt = out + (size_t)sel * 262144;
  } else if (bidx < 512) {
    local = bidx - 256; W = W4; K = 512; N = 2048; Wt = out + 1048576;
  } else {
    local = bidx - 512; W = W5; K = 2048; N = 512; Wt = out + 2097152;
  }
  int ntn = N >> 6;
  int tn = (local & (ntn - 1)) << 6, tk = (local / ntn) << 6;
  __shared__ float tile[64][65];
  int tid = threadIdx.x;
#pragma unroll
  for (int i = 0; i < 16; ++i) {
    int e = tid + i * 256, kk = e >> 6, nn = e & 63;
    tile[kk][nn] = W[(size_t)(tk + kk) * N + tn + nn];
  }
  __syncthreads();
#pragma unroll
  for (int i = 0; i < 16; ++i) {
    int e = tid + i * 256, nn = e >> 6, kk = e & 63;
    Wt[(size_t)(tn + nn) * K + tk + kk] = cvt_bf16(tile[kk][nn]);
  }
}

// --- RPE bias: tile-blocked SWIZZLED layout [b][h][qt][kt][4096] + rowmax -----
__global__ __launch_bounds__(256) void bias_kernel(
    const float* __restrict__ coords,
    const float* __restrict__ W_r1, const float* __restrict__ b_r1,
    const float* __restrict__ W_r2, const float* __restrict__ b_r2,
    unsigned short* __restrict__ bias_out, float* __restrict__ rowmax_out) {
  int kt = blockIdx.x, qt = blockIdx.y, b = blockIdx.z;
  int tid = threadIdx.x;
  int qL = tid >> 2;
  int q = qt * 64 + qL;
  int k0 = kt * 32 + (tid & 3) * 8;
  float cq0 = coords[((size_t)b * NN + q) * 2 + 0];
  float cq1 = coords[((size_t)b * NN + q) * 2 + 1];
  float Aq[16];
#pragma unroll
  for (int l = 0; l < 16; ++l)
    Aq[l] = fmaf(cq0, W_r1[l], fmaf(cq1, W_r1[16 + l], b_r1[l]));
  float ck0[8], ck1[8];
#pragma unroll
  for (int kk = 0; kk < 8; ++kk) {
    ck0[kk] = coords[((size_t)b * NN + k0 + kk) * 2 + 0];
    ck1[kk] = coords[((size_t)b * NN + k0 + kk) * 2 + 1];
  }
  float acc[8][8];
#pragma unroll
  for (int kk = 0; kk < 8; ++kk)
#pragma unroll
    for (int h = 0; h < 8; ++h) acc[kk][h] = b_r2[h];
#pragma unroll
  for (int l = 0; l < 16; ++l) {
    float w1a = W_r1[l], w1b = W_r1[16 + l];
#pragma unroll
    for (int kk = 0; kk < 8; ++kk) {
      float hv = Aq[l] - fmaf(ck0[kk], w1a, ck1[kk] * w1b);
      hv = fmaxf(hv, 0.f);
#pragma unroll
      for (int h = 0; h < 8; ++h)
        acc[kk][h] = fmaf(hv, W_r2[l * HH + h], acc[kk][h]);
    }
  }
  int elem = (qL * 64 + (kt & 1) * 32 + (tid & 3) * 8) ^ ((qL & 7) << 3);
  float mk[8];
#pragma unroll
  for (int h = 0; h < 8; ++h) {
    float m = acc[0][h];
#pragma unroll
    for (int kk = 1; kk < 8; ++kk) m = fmaxf(m, acc[kk][h]);
    m = fmaxf(m, __shfl_xor(m, 1));
    m = fmaxf(m, __shfl_xor(m, 2));
    mk[h] = m;
    bf16x8 ov;
#pragma unroll
    for (int kk = 0; kk < 8; ++kk) ov[kk] = (short)cvt_bf16(acc[kk][h]);
    size_t tile = (((size_t)b * HH + h) * 16 + qt) * 16 + (kt >> 1);
    *(bf16x8*)&bias_out[tile * 4096 + elem] = ov;
  }
  if ((tid & 3) == 0) {
#pragma unroll
    for (int h = 0; h < 8; ++h)
      rowmax_out[(((size_t)b * HH + h) * NN + q) * 32 + kt] = mk[h];
  }
}

// ------ PE add + dual LayerNorm -> bf16 + bf16 x copy (vectorized x4) ---------
__global__ __launch_bounds__(512) void pe_ln_kernel(
    const float* __restrict__ x, const float* __restrict__ coords,
    const float* __restrict__ W_pe, const float* __restrict__ b_pe,
    const float* __restrict__ g_q, const float* __restrict__ bt_q,
    const float* __restrict__ g_k, const float* __restrict__ bt_k,
    unsigned short* __restrict__ q_lnb, unsigned short* __restrict__ k_lnb,
    unsigned short* __restrict__ x_bf) {
  int tid = threadIdx.x;
  int g = tid >> 7, t = tid & 127;
  int row = blockIdx.x * 4 + g;
  int e0 = t * 4;
  float c0 = coords[(size_t)row * 2 + 0];
  float c1 = coords[(size_t)row * 2 + 1];
  size_t base = (size_t)row * DD + e0;
  f32x4 xv = *(const f32x4*)&x[base];
  f32x4 wp0 = *(const f32x4*)&W_pe[e0];
  f32x4 wp1 = *(const f32x4*)&W_pe[DD + e0];
  f32x4 bp  = *(const f32x4*)&b_pe[e0];
  u16x4 xb;
#pragma unroll
  for (int j = 0; j < 4; ++j) xb[j] = cvt_bf16(xv[j]);
  *(u16x4*)&x_bf[base] = xb;
  f32x4 val;
#pragma unroll
  for (int j = 0; j < 4; ++j)
    val[j] = xv[j] + c0 * wp0[j] + c1 * wp1[j] + bp[j];

  __shared__ float ws[8], ws2[8];
  float s = wave_sum(val[0] + val[1] + val[2] + val[3]);
  if ((tid & 63) == 0) ws[tid >> 6] = s;
  __syncthreads();
  float mean = (ws[2 * g] + ws[2 * g + 1]) * (1.f / DD);
  f32x4 dv;
  float s2l = 0.f;
#pragma unroll
  for (int j = 0; j < 4; ++j) { dv[j] = val[j] - mean; s2l = fmaf(dv[j], dv[j], s2l); }
  float s2 = wave_sum(s2l);
  if ((tid & 63) == 0) ws2[tid >> 6] = s2;
  __syncthreads();
  float var = (ws2[2 * g] + ws2[2 * g + 1]) * (1.f / DD);
  float rstd = rsqrtf(var + 1e-5f);
  f32x4 gq = *(const f32x4*)&g_q[e0], bq = *(const f32x4*)&bt_q[e0];
  f32x4 gk = *(const f32x4*)&g_k[e0], bk = *(const f32x4*)&bt_k[e0];
  u16x4 qo, ko;
#pragma unroll
  for (int j = 0; j < 4; ++j) {
    qo[j] = cvt_bf16(dv[j] * rstd * gq[j] + bq[j]);
    ko[j] = cvt_bf16(dv[j] * rstd * gk[j] + bk[j]);
  }
  *(u16x4*)&q_lnb[base] = qo;
  *(u16x4*)&k_lnb[base] = ko;
}

// ---------- residual add + LayerNorm (vectorized x4, f32 + optional bf16) -----
__global__ __launch_bounds__(512) void add_ln_kernel(
    const float* __restrict__ a, const float* __restrict__ r,
    const float* __restrict__ g_, const float* __restrict__ bt,
    float* __restrict__ out, unsigned short* __restrict__ out_bf) {
  int tid = threadIdx.x;
  int g = tid >> 7, t = tid & 127;
  int row = blockIdx.x * 4 + g;
  int e0 = t * 4;
  size_t base = (size_t)row * DD + e0;
  f32x4 av = *(const f32x4*)&a[base];
  f32x4 rv = *(const f32x4*)&r[base];
  f32x4 val;
#pragma unroll
  for (int j = 0; j < 4; ++j) val[j] = av[j] + rv[j];
  __shared__ float ws[8], ws2[8];
  float s = wave_sum(val[0] + val[1] + val[2] + val[3]);
  if ((tid & 63) == 0) ws[tid >> 6] = s;
  __syncthreads();
  float mean = (ws[2 * g] + ws[2 * g + 1]) * (1.f / DD);
  f32x4 dv;
  float s2l = 0.f;
#pragma unroll
  for (int j = 0; j < 4; ++j) { dv[j] = val[j] - mean; s2l = fmaf(dv[j], dv[j], s2l); }
  float s2 = wave_sum(s2l);
  if ((tid & 63) == 0) ws2[tid >> 6] = s2;
  __syncthreads();
  float var = (ws2[2 * g] + ws2[2 * g + 1]) * (1.f / DD);
  float rstd = rsqrtf(var + 1e-5f);
  f32x4 gg = *(const f32x4*)&g_[e0], bb = *(const f32x4*)&bt[e0];
  f32x4 ov;
  u16x4 ob;
#pragma unroll
  for (int j = 0; j < 4; ++j) {
    ov[j] = dv[j] * rstd * gg[j] + bb[j];
    ob[j] = cvt_bf16(ov[j]);
  }
  *(f32x4*)&out[base] = ov;
  if (out_bf) *(u16x4*)&out_bf[base] = ob;
}

// ---------------- bf16 MFMA GEMM 128x128: C = act(A @ BT^T + bias) ------------
template <int ACT, int EPI>
__global__ __launch_bounds__(256) void mgemm_kernel(
    const unsigned short* __restrict__ A, const unsigned short* __restrict__ BT,
    const float* __restrict__ bias, void* __restrict__ C,
    int M, int Nc, int K) {
  __shared__ unsigned short lds[4][8192];
  int tid = threadIdx.x;
  int w = tid >> 6, lane = tid & 63, lg = lane >> 4, lr = lane & 15;
  int bm = blockIdx.y * 128, bn = blockIdx.x * 128;
  int wr = w >> 1, wc = w & 1;
  int segl = lane >> 3;
  int cb = (lane & 7) << 4;

  f32x4 zf = {0.f, 0.f, 0.f, 0.f};
  f32x4 acc[4][4];
#pragma unroll
  for (int mi = 0; mi < 4; ++mi)
#pragma unroll
    for (int ni = 0; ni < 4; ++ni) acc[mi][ni] = zf;

  int nt = K >> 6;

  auto STAGE = [&](int buf, int t) {
    int k0 = t << 6;
#pragma unroll
    for (int i = 0; i < 4; ++i) {
      int seg = w * 4 + i;
      int r = (seg << 3) + segl;
      int csw = cb ^ ((r & 7) << 4);
      const char* ga = (const char*)A + (((size_t)(bm + r) * K + k0) << 1) + csw;
      gl_lds16(ga, &lds[buf * 2][seg << 9]);
      const char* gb = (const char*)BT + (((size_t)(bn + r) * K + k0) << 1) + csw;
      gl_lds16(gb, &lds[buf * 2 + 1][seg << 9]);
    }
  };
  auto COMPUTE = [&](int buf) {
    const unsigned short* As = lds[buf * 2];
    const unsigned short* Bs = lds[buf * 2 + 1];
    bf16x8 af[2][4], bfr[2][4];
#pragma unroll
    for (int kh = 0; kh < 2; ++kh)
#pragma unroll
      for (int mi = 0; mi < 4; ++mi) {
        int r = wr * 64 + mi * 16 + lr;
        int e = (r << 6) + (kh << 5) + (lg << 3);
        af[kh][mi] = *(const bf16x8*)&As[e ^ ((r & 7) << 3)];
        int rb = wc * 64 + mi * 16 + lr;
        int eb = (rb << 6) + (kh << 5) + (lg << 3);
        bfr[kh][mi] = *(const bf16x8*)&Bs[eb ^ ((rb & 7) << 3)];
      }
#pragma unroll
    for (int kh = 0; kh < 2; ++kh)
#pragma unroll
      for (int mi = 0; mi < 4; ++mi)
#pragma unroll
        for (int ni = 0; ni < 4; ++ni)
          acc[mi][ni] = __builtin_amdgcn_mfma_f32_16x16x32_bf16(
              af[kh][mi], bfr[kh][ni], acc[mi][ni], 0, 0, 0);
  };

  STAGE(0, 0);
  __syncthreads();
  for (int t = 0; t < nt; ++t) {
    if (t + 1 < nt) STAGE((t + 1) & 1, t + 1);
    COMPUTE(t & 1);
    __syncthreads();
  }

#pragma unroll
  for (int ni = 0; ni < 4; ++ni) {
    int col = bn + wc * 64 + ni * 16 + lr;
    float bv = bias ? bias[col] : 0.f;
#pragma unroll
    for (int mi = 0; mi < 4; ++mi) {
#pragma unroll
      for (int j = 0; j < 4; ++j) {
        int row = bm + wr * 64 + mi * 16 + lg * 4 + j;
        float v = acc[mi][ni][j] + bv;
        if (ACT == 1) v = v > 0.f ? v : 0.2f * v;
        if (EPI == 1)
          ((unsigned short*)C)[(size_t)row * Nc + col] = cvt_bf16(v);
        else
          ((float*)C)[(size_t)row * Nc + col] = v;
      }
    }
  }
}

// ------------- bf16 MFMA GEMM 64x64 tile (2x grid for small-N GEMMs) ----------
template <int ACT, int EPI>
__global__ __launch_bounds__(256) void mgemm64_kernel(
    const unsigned short* __restrict__ A, const unsigned short* __restrict__ BT,
    const float* __restrict__ bias, void* __restrict__ C,
    int M, int Nc, int K) {
  __shared__ unsigned short lds[4][4096];
  int tid = threadIdx.x;
  int w = tid >> 6, lane = tid & 63, lg = lane >> 4, lr = lane & 15;
  int bm = blockIdx.y * 64, bn = blockIdx.x * 64;
  int wr = w >> 1, wc = w & 1;
  int segl = lane >> 3;
  int cb = (lane & 7) << 4;

  f32x4 zf = {0.f, 0.f, 0.f, 0.f};
  f32x4 acc[2][2];
#pragma unroll
  for (int mi = 0; mi < 2; ++mi)
#pragma unroll
    for (int ni = 0; ni < 2; ++ni) acc[mi][ni] = zf;

  int nt = K >> 6;

  auto STAGE = [&](int buf, int t) {
    int k0 = t << 6;
#pragma unroll
    for (int i = 0; i < 2; ++i) {
      int seg = w * 2 + i;
      int r = (seg << 3) + segl;
      int csw = cb ^ ((r & 7) << 4);
      const char* ga = (const char*)A + (((size_t)(bm + r) * K + k0) << 1) + csw;
      gl_lds16(ga, &lds[buf * 2][seg << 9]);
      const char* gb = (const char*)BT + (((size_t)(bn + r) * K + k0) << 1) + csw;
      gl_lds16(gb, &lds[buf * 2 + 1][seg << 9]);
    }
  };
  auto COMPUTE = [&](int buf) {
    const unsigned short* As = lds[buf * 2];
    const unsigned short* Bs = lds[buf * 2 + 1];
    bf16x8 af[2][2], bfr[2][2];
#pragma unroll
    for (int kh = 0; kh < 2; ++kh)
#pragma unroll
      for (int mi = 0; mi < 2; ++mi) {
        int r = wr * 32 + mi * 16 + lr;
        int e = (r << 6) + (kh << 5) + (lg << 3);
        af[kh][mi] = *(const bf16x8*)&As[e ^ ((r & 7) << 3)];
        int rb = wc * 32 + mi * 16 + lr;
        int eb = (rb << 6) + (kh << 5) + (lg << 3);
        bfr[kh][mi] = *(const bf16x8*)&Bs[eb ^ ((rb & 7) << 3)];
      }
#pragma unroll
    for (int kh = 0; kh < 2; ++kh)
#pragma unroll
      for (int mi = 0; mi < 2; ++mi)
#pragma unroll
        for (int ni = 0; ni < 2; ++ni)
          acc[mi][ni] = __builtin_amdgcn_mfma_f32_16x16x32_bf16(
              af[kh][mi], bfr[kh][ni], acc[mi][ni], 0, 0, 0);
  };

  STAGE(0, 0);
  __syncthreads();
  for (int t = 0; t < nt; ++t) {
    if (t + 1 < nt) STAGE((t + 1) & 1, t + 1);
    COMPUTE(t & 1);
    __syncthreads();
  }

#pragma unroll
  for (int ni = 0; ni < 2; ++ni) {
    int col = bn + wc * 32 + ni * 16 + lr;
    float bv = bias ? bias[col] : 0.f;
#pragma unroll
    for (int mi = 0; mi < 2; ++mi) {
#pragma unroll
      for (int j = 0; j < 4; ++j) {
        int row = bm + wr * 32 + mi * 16 + lg * 4 + j;
        float v = acc[mi][ni][j] + bv;
        if (ACT == 1) v = v > 0.f ? v : 0.2f * v;
        if (EPI == 1)
          ((unsigned short*)C)[(size_t)row * Nc + col] = cvt_bf16(v);
        else
          ((float*)C)[(size_t)row * Nc + col] = v;
      }
    }
  }
}

// ---------- fused QKV GEMM (z: 0=q norm, 1=k norm, 2=v -> V^T plain) ----------
__global__ __launch_bounds__(256) void qkv_gemm_kernel(
    const unsigned short* __restrict__ q_lnb,
    const unsigned short* __restrict__ k_lnb,
    const unsigned short* __restrict__ x_bf,
    const unsigned short* __restrict__ wt,
    const float* __restrict__ bq, const float* __restrict__ bk,
    const float* __restrict__ bv_,
    unsigned short* __restrict__ q_bf, unsigned short* __restrict__ k_bf,
    unsigned short* __restrict__ vt_g) {
  int z = blockIdx.z;
  const unsigned short* A = z == 0 ? q_lnb : z == 1 ? k_lnb : x_bf;
  const unsigned short* BT = wt + (size_t)z * 262144;
  const float* bias = z == 0 ? bq : z == 1 ? bk : bv_;

  __shared__ unsigned short lds[4][8192];
  int tid = threadIdx.x;
  int w = tid >> 6, lane = tid & 63, lg = lane >> 4, lr = lane & 15;
  int bm = blockIdx.y * 128, bn = blockIdx.x * 128;
  int wr = w >> 1, wc = w & 1;
  int segl = lane >> 3;
  int cb = (lane & 7) << 4;

  f32x4 zf = {0.f, 0.f, 0.f, 0.f};
  f32x4 acc[4][4];
#pragma unroll
  for (int mi = 0; mi < 4; ++mi)
#pragma unroll
    for (int ni = 0; ni < 4; ++ni) acc[mi][ni] = zf;

  auto STAGE = [&](int buf, int t) {
    int k0 = t << 6;
#pragma unroll
    for (int i = 0; i < 4; ++i) {
      int seg = w * 4 + i;
      int r = (seg << 3) + segl;
      int csw = cb ^ ((r & 7) << 4);
      const char* ga = (const char*)A + (((size_t)(bm + r) * DD + k0) << 1) + csw;
      gl_lds16(ga, &lds[buf * 2][seg << 9]);
      const char* gb = (const char*)BT + (((size_t)(bn + r) * DD + k0) << 1) + csw;
      gl_lds16(gb, &lds[buf * 2 + 1][seg << 9]);
    }
  };
  auto COMPUTE = [&](int buf) {
    const unsigned short* As = lds[buf * 2];
    const unsigned short* Bs = lds[buf * 2 + 1];
    bf16x8 af[2][4], bfr[2][4];
#pragma unroll
    for (int kh = 0; kh < 2; ++kh)
#pragma unroll
      for (int mi = 0; mi < 4; ++mi) {
        int r = wr * 64 + mi * 16 + lr;
        int e = (r << 6) + (kh << 5) + (lg << 3);
        af[kh][mi] = *(const bf16x8*)&As[e ^ ((r & 7) << 3)];
        int rb = wc * 64 + mi * 16 + lr;
        int eb = (rb << 6) + (kh << 5) + (lg << 3);
        bfr[kh][mi] = *(const bf16x8*)&Bs[eb ^ ((rb & 7) << 3)];
      }
#pragma unroll
    for (int kh = 0; kh < 2; ++kh)
#pragma unroll
      for (int mi = 0; mi < 4; ++mi)
#pragma unroll
        for (int ni = 0; ni < 4; ++ni)
          acc[mi][ni] = __builtin_amdgcn_mfma_f32_16x16x32_bf16(
              af[kh][mi], bfr[kh][ni], acc[mi][ni], 0, 0, 0);
  };

  STAGE(0, 0);
  __syncthreads();
  for (int t = 0; t < 8; ++t) {
    if (t + 1 < 8) STAGE((t + 1) & 1, t + 1);
    COMPUTE(t & 1);
    __syncthreads();
  }

  int h = (bn >> 6) + wc;
  float bvf[4];
#pragma unroll
  for (int ni = 0; ni < 4; ++ni) bvf[ni] = bias[bn + wc * 64 + ni * 16 + lr];
#pragma unroll
  for (int mi = 0; mi < 4; ++mi) {
#pragma unroll
    for (int j = 0; j < 4; ++j) {
      float vals[4]; float ss = 0.f;
#pragma unroll
      for (int ni = 0; ni < 4; ++ni) {
        float v = acc[mi][ni][j] + bvf[ni];
        vals[ni] = v;
        ss = fmaf(v, v, ss);
      }
      float rn = 1.f;
      if (z <= 1) {
        ss += __shfl_xor(ss, 1);
        ss += __shfl_xor(ss, 2);
        ss += __shfl_xor(ss, 4);
        ss += __shfl_xor(ss, 8);
        rn = 1.f / fmaxf(sqrtf(ss), 1e-12f);
      }
      int row = bm + wr * 64 + mi * 16 + lg * 4 + j;
      int b_ = row >> 10, n_ = row & (NN - 1);
      if (z <= 1) {
        unsigned short* ob = (z == 0 ? q_bf : k_bf) +
                             (((size_t)b_ * HH + h) * NN + n_) * DHH;
#pragma unroll
        for (int ni = 0; ni < 4; ++ni)
          ob[ni * 16 + lr] = cvt_bf16(vals[ni] * rn);
      } else {
#pragma unroll
        for (int ni = 0; ni < 4; ++ni)
          vt_g[(((size_t)b_ * HH + h) * DHH + ni * 16 + lr) * NN + n_] =
              cvt_bf16(vals[ni]);
      }
    }
  }
}

// ---- MFMA flash attention: all NT bias tiles prologue-staged via gl_lds16 ----
// ---- (contiguous 32KB bursts); K/V direct contiguous 16B global loads. -------
// ---- One-pass softmax via precomputed row m_ub; NSPLIT = 16/NT. --------------
template <int NT>
__global__ __launch_bounds__(256) void attn_vres_kernel(
    const unsigned short* __restrict__ qb, const unsigned short* __restrict__ kb,
    const unsigned short* __restrict__ vtg,
    const unsigned short* __restrict__ bias_t,
    const float* __restrict__ rowmax_g,
    const float* __restrict__ logit_scale,
    unsigned short* __restrict__ part, int nb) {
  int qt = blockIdx.x, h = blockIdx.y;
  int b = blockIdx.z % nb, sp = blockIdx.z / nb;
  int tid = threadIdx.x;
  int w = tid >> 6, lane = tid & 63;
  int lg = lane >> 4, lr = lane & 15;

  __shared__ unsigned short bl[NT][4096];   // bias tiles, pre-swizzled
  __shared__ unsigned short pl[4][1024];    // per-wave P, swizzled

  const size_t bh = ((size_t)b * HH + h) * NN;
  const size_t vbase = ((size_t)b * HH + h) * DHH * NN;
  const int kt0 = sp * NT;

  int q_glob = qt * 64 + w * 16 + lr;
  bf16x8 aq0 = *(const bf16x8*)&qb[(bh + q_glob) * DHH + lg * 8];
  bf16x8 aq1 = *(const bf16x8*)&qb[(bh + q_glob) * DHH + 32 + lg * 8];

  float m_ub[4];
  float scale_h = __expf(fminf(logit_scale[h], 4.605170185988091f));
#pragma unroll
  for (int r = 0; r < 4; ++r) {
    int qg = qt * 64 + w * 16 + lg * 4 + r;
    const float* rmp = &rowmax_g[(bh + qg) * 32];
    float rm = -1e30f;
#pragma unroll
    for (int i = 0; i < 8; ++i) {
      f32x4 v = *(const f32x4*)&rmp[i * 4];
      rm = fmaxf(rm, fmaxf(fmaxf(v[0], v[1]), fmaxf(v[2], v[3])));
    }
    m_ub[r] = rm + 1.05f * scale_h + 0.1f;
  }

  float l_run[4] = {0.f, 0.f, 0.f, 0.f};
  f32x4 zf = {0.f, 0.f, 0.f, 0.f};
  f32x4 acc_o[4] = {zf, zf, zf, zf};

  // prologue: stage all NT bias tiles (contiguous 8KB bursts), one barrier
  const unsigned short* bbase =
      bias_t + ((((size_t)b * HH + h) * 16 + qt) * 16 + kt0) * 4096;
#pragma unroll
  for (int t = 0; t < NT; ++t) {
#pragma unroll
    for (int i = 0; i < 2; ++i) {
      int chunk = i * 256 + w * 64;          // wave-uniform 16B-chunk base
      gl_lds16(bbase + (size_t)t * 4096 + (size_t)(chunk + lane) * 8,
               &bl[t][chunk * 8]);
    }
  }
  __syncthreads();

  // main loop: K/V direct 16B global loads, bias from LDS, no barriers
  for (int t = 0; t < NT; ++t) {
    int ktg = kt0 + t;

    f32x4 s_acc[4];
#pragma unroll
    for (int kc = 0; kc < 4; ++kc) {
      const unsigned short* krow =
          &kb[(bh + ktg * 64 + kc * 16 + lr) * DHH + lg * 8];
      bf16x8 bk0 = *(const bf16x8*)krow;
      bf16x8 bk1 = *(const bf16x8*)(krow + 32);
      s_acc[kc] = __builtin_amdgcn_mfma_f32_16x16x32_bf16(aq0, bk0, zf, 0, 0, 0);
      s_acc[kc] = __builtin_amdgcn_mfma_f32_16x16x32_bf16(aq1, bk1, s_acc[kc], 0, 0, 0);
    }

    // one-pass softmax with precomputed m_ub
#pragma unroll
    for (int kc = 0; kc < 4; ++kc)
#pragma unroll
      for (int r = 0; r < 4; ++r) {
        int q = w * 16 + lg * 4 + r;
        unsigned short ub = bl[t][(q * 64 + kc * 16 + lr) ^ ((q & 7) << 3)];
        float bf_ = __uint_as_float(((unsigned)ub) << 16);
        float p = __expf(fmaf(s_acc[kc][r], scale_h, bf_ - m_ub[r]));
        l_run[r] += p;
        int ql = lg * 4 + r;
        pl[w][(ql * 64 + kc * 16 + lr) ^ ((ql & 7) << 3)] = cvt_bf16(p);
      }

#pragma unroll
    for (int ka = 0; ka < 2; ++ka) {
      bf16x8 pa = *(const bf16x8*)&pl[w][(lr * 64 + ka * 32 + lg * 8) ^
                                         ((lr & 7) << 3)];
#pragma unroll
      for (int ds = 0; ds < 4; ++ds) {
        int d = ds * 16 + lr;
        bf16x8 bv = *(const bf16x8*)&vtg[vbase + (size_t)d * NN +
                                         ktg * 64 + ka * 32 + lg * 8];
        acc_o[ds] = __builtin_amdgcn_mfma_f32_16x16x32_bf16(pa, bv, acc_o[ds], 0, 0, 0);
      }
    }
  }

#pragma unroll
  for (int r = 0; r < 4; ++r) {
    l_run[r] += __shfl_xor(l_run[r], 1);
    l_run[r] += __shfl_xor(l_run[r], 2);
    l_run[r] += __shfl_xor(l_run[r], 4);
    l_run[r] += __shfl_xor(l_run[r], 8);
  }

#pragma unroll
  for (int r = 0; r < 4; ++r) {
    int qg = qt * 64 + w * 16 + lg * 4 + r;
    size_t idx = ((size_t)(sp * nb + b) * HH + h) * NN + qg;
    unsigned short* pr = part + idx * 68;
#pragma unroll
    for (int ds = 0; ds < 4; ++ds)
      pr[ds * 16 + lr] = cvt_bf16(acc_o[ds][r]);
    if (lr == 0) *(float*)(pr + 64) = l_run[r];
  }
}

// ------- combine NS k-split partials (shared m_ub -> plain sums) --------------
template <int NS>
__global__ __launch_bounds__(256) void combine_kernel(
    const unsigned short* __restrict__ part, unsigned short* __restrict__ attb,
    int nb) {
  int tid = threadIdx.x;
  int w = tid >> 6, d = tid & 63;
  int row = blockIdx.x * 4 + w;
  int nrow = nb * HH * NN;
  if (row >= nrow) return;
  int b = row / (HH * NN), rem = row % (HH * NN), h = rem >> 10, n = rem & (NN - 1);
  size_t i0 = ((size_t)b * HH + h) * NN + n;
  size_t stride = (size_t)nb * HH * NN;
  float num = 0.f, den = 0.f;
#pragma unroll
  for (int s = 0; s < NS; ++s) {
    const unsigned short* p = part + (i0 + s * stride) * 68;
    num += __uint_as_float(((unsigned)p[d]) << 16);
    den += *(const float*)(p + 64);
  }
  attb[((size_t)b * NN + n) * DD + h * DHH + d] = cvt_bf16(num / den);
}

// ---------------- launcher ----------------
extern "C" void kernel_launch(void* const* d_in, const int* in_sizes, int n_in,
                              void* d_out, int out_size, void* d_ws, size_t ws_size,
                              hipStream_t stream) {
  const float* x      = (const float*)d_in[0];
  const float* coords = (const float*)d_in[1];
  const float* Wq = (const float*)d_in[2];  const float* bq = (const float*)d_in[3];
  const float* Wk = (const float*)d_in[4];  const float* bk = (const float*)d_in[5];
  const float* Wv = (const float*)d_in[6];  const float* bv = (const float*)d_in[7];
  const float* Wo = (const float*)d_in[8];  const float* bo = (const float*)d_in[9];
  const float* logit_scale = (const float*)d_in[10];
  const float* W_pe = (const float*)d_in[11]; const float* b_pe = (const float*)d_in[12];
  const float* W_r1 = (const float*)d_in[13]; const float* b_r1 = (const float*)d_in[14];
  const float* W_r2 = (const float*)d_in[15]; const float* b_r2 = (const float*)d_in[16];
  const float* g_peq = (const float*)d_in[17]; const float* bt_peq = (const float*)d_in[18];
  const float* g_pek = (const float*)d_in[19]; const float* bt_pek = (const float*)d_in[20];
  const float* g2 = (const float*)d_in[21]; const float* bt2 = (const float*)d_in[22];
  const float* g3 = (const float*)d_in[23]; const float* bt3 = (const float*)d_in[24];
  const float* W_ff1 = (const float*)d_in[25];
  const float* W_ff2 = (const float*)d_in[26];
  float* out = (float*)d_out;

  const size_t T = (size_t)BB * NN;
  char* wsb = (char*)d_ws;
  const size_t U = 4u * 1024u * 1024u;

  unsigned short* wt_all = (unsigned short*)(wsb + 0 * U);   // [0,2U)
  unsigned short* WoT   = wt_all + 786432;
  unsigned short* Wff1T = wt_all + 1048576;
  unsigned short* Wff2T = wt_all + 2097152;
  unsigned short* q_lnb = (unsigned short*)(wsb + 2 * U);
  unsigned short* k_lnb = (unsigned short*)(wsb + 3 * U);
  unsigned short* x_bf  = (unsigned short*)(wsb + 4 * U);
  unsigned short* q_bf  = (unsigned short*)(wsb + 5 * U);
  unsigned short* k_bf  = (unsigned short*)(wsb + 6 * U);
  unsigned short* v_bf  = (unsigned short*)(wsb + 7 * U);    // V^T [B,H,64,N]
  unsigned short* att_bf = (unsigned short*)(wsb + 8 * U);
  float* proj = (float*)(wsb + 9 * U);                        // [9U,11U)
  float* x1   = (float*)(wsb + 11 * U);                       // [11U,13U)
  unsigned short* x1_bf = (unsigned short*)(wsb + 13 * U);    // [13U,14U)
  unsigned short* hid_bf = (unsigned short*)(wsb + 2 * U);    // [2U,6U)
  float* mlp  = (float*)(wsb + 9 * U);
  // attention-phase overlays (dead regions during attention):
  float* rowmax_ws = (float*)(wsb + 2 * U);                   // 4 MiB [2U,3U)
  unsigned short* bias_ws = (unsigned short*)(wsb + 9 * U);   // 64 MiB [9U,25U)
  unsigned short* part_ws = (unsigned short*)(wsb + 25 * U);  // 17.8 MiB

  wconv_kernel<<<dim3(768), dim3(256), 0, stream>>>(
      Wq, Wk, Wv, Wo, W_ff1, W_ff2, wt_all);

  pe_ln_kernel<<<dim3(T / 4), dim3(512), 0, stream>>>(
      x, coords, W_pe, b_pe, g_peq, bt_peq, g_pek, bt_pek, q_lnb, k_lnb, x_bf);

  qkv_gemm_kernel<<<dim3(DD / 128, T / 128, 3), dim3(256), 0, stream>>>(
      q_lnb, k_lnb, x_bf, wt_all, bq, bk, bv, q_bf, k_bf, v_bf);

  if (ws_size >= 30 * U) {
    // NSPLIT=4, NT=4: 2048 blocks, 40KB LDS, 32KB contiguous bias bursts
    bias_kernel<<<dim3(NN / 32, NN / 64, BB), dim3(256), 0, stream>>>(
        coords, W_r1, b_r1, W_r2, b_r2, bias_ws, rowmax_ws);
    attn_vres_kernel<4><<<dim3(NN / 64, HH, 4 * BB), dim3(256), 0, stream>>>(
        q_bf, k_bf, v_bf, bias_ws, rowmax_ws, logit_scale, part_ws, BB);
    combine_kernel<4><<<dim3(BB * HH * NN / 4), dim3(256), 0, stream>>>(
        part_ws, att_bf, BB);
  } else {
    // per-batch: bias 16MB [9U,13U), part 4.5MB [13U,~14.2U), rowmax [2U,3U)
    unsigned short* bias_b = (unsigned short*)(wsb + 9 * U);
    unsigned short* part_b = (unsigned short*)(wsb + 13 * U);
    float* rm_b = (float*)(wsb + 2 * U);
    for (int b = 0; b < BB; ++b) {
      bias_kernel<<<dim3(NN / 32, NN / 64, 1), dim3(256), 0, stream>>>(
          coords + (size_t)b * NN * 2, W_r1, b_r1, W_r2, b_r2, bias_b, rm_b);
      attn_vres_kernel<4><<<dim3(NN / 64, HH, 4), dim3(256), 0, stream>>>(
          q_bf + (size_t)b * HH * NN * DHH, k_bf + (size_t)b * HH * NN * DHH,
          v_bf + (size_t)b * HH * DHH * NN, bias_b, rm_b, logit_scale,
          part_b, 1);
      combine_kernel<4><<<dim3(HH * NN / 4), dim3(256), 0, stream>>>(
          part_b, att_bf + (size_t)b * NN * DD, 1);
    }
  }

  mgemm64_kernel<0, 0><<<dim3(DD / 64, T / 64), dim3(256), 0, stream>>>(
      att_bf, WoT, bo, proj, (int)T, DD, DD);

  add_ln_kernel<<<dim3(T / 4), dim3(512), 0, stream>>>(
      x, proj, g2, bt2, x1, x1_bf);

  mgemm_kernel<1, 1><<<dim3(FFF / 128, T / 128), dim3(256), 0, stream>>>(
      x1_bf, Wff1T, nullptr, hid_bf, (int)T, FFF, DD);
  mgemm64_kernel<1, 0><<<dim3(DD / 64, T / 64), dim3(256), 0, stream>>>(
      hid_bf, Wff2T, nullptr, mlp, (int)T, DD, FFF);

  add_ln_kernel<<<dim3(T / 4), dim3(512), 0, stream>>>(
      x1, mlp, g3, bt3, out, nullptr);
}

// Round 17
// 166.919 us; speedup vs baseline: 1.2187x; 1.2187x over previous
//
#include <hip/hip_runtime.h>

#define BB 4
#define NN 1024
#define DD 512
#define HH 8
#define DHH 64
#define FFF 2048

typedef __attribute__((ext_vector_type(8))) short bf16x8;
typedef __attribute__((ext_vector_type(4))) float f32x4;
typedef __attribute__((ext_vector_type(4))) unsigned short u16x4;

__device__ inline float wave_sum(float v) {
#pragma unroll
  for (int off = 32; off; off >>= 1) v += __shfl_xor(v, off);
  return v;
}

__device__ inline unsigned short cvt_bf16(float f) {
  union { float f; unsigned u; } x;
  x.f = f;
  unsigned r = x.u + 0x7FFFu + ((x.u >> 16) & 1u);
  return (unsigned short)(r >> 16);
}

__device__ __forceinline__ void gl_lds16(const void* g, void* l) {
  __builtin_amdgcn_global_load_lds(
      (__attribute__((address_space(1))) void*)(g),
      (__attribute__((address_space(3))) void*)(l), 16, 0, 0);
}

// ---------------- weight transpose + bf16 convert (all 6 weights, 1 launch) ----
__global__ __launch_bounds__(256) void wconv_kernel(
    const float* __restrict__ W0, const float* __restrict__ W1,
    const float* __restrict__ W2, const float* __restrict__ W3,
    const float* __restrict__ W4, const float* __restrict__ W5,
    unsigned short* __restrict__ out) {
  int bidx = blockIdx.x;
  const float* W; unsigned short* Wt; int K, N, local;
  if (bidx < 256) {
    int sel = bidx >> 6; local = bidx & 63;
    W = sel == 0 ? W0 : sel == 1 ? W1 : sel == 2 ? W2 : W3;
    K = 512; N = 512; Wt = out + (size_t)sel * 262144;
  } else if (bidx < 512) {
    local = bidx - 256; W = W4; K = 512; N = 2048; Wt = out + 1048576;
  } else {
    local = bidx - 512; W = W5; K = 2048; N = 512; Wt = out + 2097152;
  }
  int ntn = N >> 6;
  int tn = (local & (ntn - 1)) << 6, tk = (local / ntn) << 6;
  __shared__ float tile[64][65];
  int tid = threadIdx.x;
#pragma unroll
  for (int i = 0; i < 16; ++i) {
    int e = tid + i * 256, kk = e >> 6, nn = e & 63;
    tile[kk][nn] = W[(size_t)(tk + kk) * N + tn + nn];
  }
  __syncthreads();
#pragma unroll
  for (int i = 0; i < 16; ++i) {
    int e = tid + i * 256, nn = e >> 6, kk = e & 63;
    Wt[(size_t)(tn + nn) * K + tk + kk] = cvt_bf16(tile[kk][nn]);
  }
}

// ---------------- RPE bias materialization: bias[nb,H,N,N] bf16 (row-major) ----
__global__ __launch_bounds__(256) void bias_kernel(
    const float* __restrict__ coords,
    const float* __restrict__ W_r1, const float* __restrict__ b_r1,
    const float* __restrict__ W_r2, const float* __restrict__ b_r2,
    unsigned short* __restrict__ bias_out) {
  int kt = blockIdx.x, qt = blockIdx.y, b = blockIdx.z;
  int tid = threadIdx.x;
  int q = qt * 64 + (tid >> 2);
  int k0 = kt * 32 + (tid & 3) * 8;
  float cq0 = coords[((size_t)b * NN + q) * 2 + 0];
  float cq1 = coords[((size_t)b * NN + q) * 2 + 1];
  float Aq[16];
#pragma unroll
  for (int l = 0; l < 16; ++l)
    Aq[l] = fmaf(cq0, W_r1[l], fmaf(cq1, W_r1[16 + l], b_r1[l]));
  float ck0[8], ck1[8];
#pragma unroll
  for (int kk = 0; kk < 8; ++kk) {
    ck0[kk] = coords[((size_t)b * NN + k0 + kk) * 2 + 0];
    ck1[kk] = coords[((size_t)b * NN + k0 + kk) * 2 + 1];
  }
  float acc[8][8];
#pragma unroll
  for (int kk = 0; kk < 8; ++kk)
#pragma unroll
    for (int h = 0; h < 8; ++h) acc[kk][h] = b_r2[h];
#pragma unroll
  for (int l = 0; l < 16; ++l) {
    float w1a = W_r1[l], w1b = W_r1[16 + l];
#pragma unroll
    for (int kk = 0; kk < 8; ++kk) {
      float hv = Aq[l] - fmaf(ck0[kk], w1a, ck1[kk] * w1b);
      hv = fmaxf(hv, 0.f);
#pragma unroll
      for (int h = 0; h < 8; ++h)
        acc[kk][h] = fmaf(hv, W_r2[l * HH + h], acc[kk][h]);
    }
  }
#pragma unroll
  for (int h = 0; h < 8; ++h) {
    bf16x8 ov;
#pragma unroll
    for (int kk = 0; kk < 8; ++kk) ov[kk] = (short)cvt_bf16(acc[kk][h]);
    *(bf16x8*)&bias_out[(((size_t)b * HH + h) * NN + q) * NN + k0] = ov;
  }
}

// ------ PE add + dual LayerNorm -> bf16 + bf16 x copy (vectorized x4) ---------
__global__ __launch_bounds__(512) void pe_ln_kernel(
    const float* __restrict__ x, const float* __restrict__ coords,
    const float* __restrict__ W_pe, const float* __restrict__ b_pe,
    const float* __restrict__ g_q, const float* __restrict__ bt_q,
    const float* __restrict__ g_k, const float* __restrict__ bt_k,
    unsigned short* __restrict__ q_lnb, unsigned short* __restrict__ k_lnb,
    unsigned short* __restrict__ x_bf) {
  int tid = threadIdx.x;
  int g = tid >> 7, t = tid & 127;
  int row = blockIdx.x * 4 + g;
  int e0 = t * 4;
  float c0 = coords[(size_t)row * 2 + 0];
  float c1 = coords[(size_t)row * 2 + 1];
  size_t base = (size_t)row * DD + e0;
  f32x4 xv = *(const f32x4*)&x[base];
  f32x4 wp0 = *(const f32x4*)&W_pe[e0];
  f32x4 wp1 = *(const f32x4*)&W_pe[DD + e0];
  f32x4 bp  = *(const f32x4*)&b_pe[e0];
  u16x4 xb;
#pragma unroll
  for (int j = 0; j < 4; ++j) xb[j] = cvt_bf16(xv[j]);
  *(u16x4*)&x_bf[base] = xb;
  f32x4 val;
#pragma unroll
  for (int j = 0; j < 4; ++j)
    val[j] = xv[j] + c0 * wp0[j] + c1 * wp1[j] + bp[j];

  __shared__ float ws[8], ws2[8];
  float s = wave_sum(val[0] + val[1] + val[2] + val[3]);
  if ((tid & 63) == 0) ws[tid >> 6] = s;
  __syncthreads();
  float mean = (ws[2 * g] + ws[2 * g + 1]) * (1.f / DD);
  f32x4 dv;
  float s2l = 0.f;
#pragma unroll
  for (int j = 0; j < 4; ++j) { dv[j] = val[j] - mean; s2l = fmaf(dv[j], dv[j], s2l); }
  float s2 = wave_sum(s2l);
  if ((tid & 63) == 0) ws2[tid >> 6] = s2;
  __syncthreads();
  float var = (ws2[2 * g] + ws2[2 * g + 1]) * (1.f / DD);
  float rstd = rsqrtf(var + 1e-5f);
  f32x4 gq = *(const f32x4*)&g_q[e0], bq = *(const f32x4*)&bt_q[e0];
  f32x4 gk = *(const f32x4*)&g_k[e0], bk = *(const f32x4*)&bt_k[e0];
  u16x4 qo, ko;
#pragma unroll
  for (int j = 0; j < 4; ++j) {
    qo[j] = cvt_bf16(dv[j] * rstd * gq[j] + bq[j]);
    ko[j] = cvt_bf16(dv[j] * rstd * gk[j] + bk[j]);
  }
  *(u16x4*)&q_lnb[base] = qo;
  *(u16x4*)&k_lnb[base] = ko;
}

// ---------- residual add + LayerNorm (vectorized x4, f32 + optional bf16) -----
__global__ __launch_bounds__(512) void add_ln_kernel(
    const float* __restrict__ a, const float* __restrict__ r,
    const float* __restrict__ g_, const float* __restrict__ bt,
    float* __restrict__ out, unsigned short* __restrict__ out_bf) {
  int tid = threadIdx.x;
  int g = tid >> 7, t = tid & 127;
  int row = blockIdx.x * 4 + g;
  int e0 = t * 4;
  size_t base = (size_t)row * DD + e0;
  f32x4 av = *(const f32x4*)&a[base];
  f32x4 rv = *(const f32x4*)&r[base];
  f32x4 val;
#pragma unroll
  for (int j = 0; j < 4; ++j) val[j] = av[j] + rv[j];
  __shared__ float ws[8], ws2[8];
  float s = wave_sum(val[0] + val[1] + val[2] + val[3]);
  if ((tid & 63) == 0) ws[tid >> 6] = s;
  __syncthreads();
  float mean = (ws[2 * g] + ws[2 * g + 1]) * (1.f / DD);
  f32x4 dv;
  float s2l = 0.f;
#pragma unroll
  for (int j = 0; j < 4; ++j) { dv[j] = val[j] - mean; s2l = fmaf(dv[j], dv[j], s2l); }
  float s2 = wave_sum(s2l);
  if ((tid & 63) == 0) ws2[tid >> 6] = s2;
  __syncthreads();
  float var = (ws2[2 * g] + ws2[2 * g + 1]) * (1.f / DD);
  float rstd = rsqrtf(var + 1e-5f);
  f32x4 gg = *(const f32x4*)&g_[e0], bb = *(const f32x4*)&bt[e0];
  f32x4 ov;
  u16x4 ob;
#pragma unroll
  for (int j = 0; j < 4; ++j) {
    ov[j] = dv[j] * rstd * gg[j] + bb[j];
    ob[j] = cvt_bf16(ov[j]);
  }
  *(f32x4*)&out[base] = ov;
  if (out_bf) *(u16x4*)&out_bf[base] = ob;
}

// ---------------- bf16 MFMA GEMM 128x128: C = act(A @ BT^T + bias) ------------
template <int ACT, int EPI>
__global__ __launch_bounds__(256) void mgemm_kernel(
    const unsigned short* __restrict__ A, const unsigned short* __restrict__ BT,
    const float* __restrict__ bias, void* __restrict__ C,
    int M, int Nc, int K) {
  __shared__ unsigned short lds[4][8192];
  int tid = threadIdx.x;
  int w = tid >> 6, lane = tid & 63, lg = lane >> 4, lr = lane & 15;
  int bm = blockIdx.y * 128, bn = blockIdx.x * 128;
  int wr = w >> 1, wc = w & 1;
  int segl = lane >> 3;
  int cb = (lane & 7) << 4;

  f32x4 zf = {0.f, 0.f, 0.f, 0.f};
  f32x4 acc[4][4];
#pragma unroll
  for (int mi = 0; mi < 4; ++mi)
#pragma unroll
    for (int ni = 0; ni < 4; ++ni) acc[mi][ni] = zf;

  int nt = K >> 6;

  auto STAGE = [&](int buf, int t) {
    int k0 = t << 6;
#pragma unroll
    for (int i = 0; i < 4; ++i) {
      int seg = w * 4 + i;
      int r = (seg << 3) + segl;
      int csw = cb ^ ((r & 7) << 4);
      const char* ga = (const char*)A + (((size_t)(bm + r) * K + k0) << 1) + csw;
      gl_lds16(ga, &lds[buf * 2][seg << 9]);
      const char* gb = (const char*)BT + (((size_t)(bn + r) * K + k0) << 1) + csw;
      gl_lds16(gb, &lds[buf * 2 + 1][seg << 9]);
    }
  };
  auto COMPUTE = [&](int buf) {
    const unsigned short* As = lds[buf * 2];
    const unsigned short* Bs = lds[buf * 2 + 1];
    bf16x8 af[2][4], bfr[2][4];
#pragma unroll
    for (int kh = 0; kh < 2; ++kh)
#pragma unroll
      for (int mi = 0; mi < 4; ++mi) {
        int r = wr * 64 + mi * 16 + lr;
        int e = (r << 6) + (kh << 5) + (lg << 3);
        af[kh][mi] = *(const bf16x8*)&As[e ^ ((r & 7) << 3)];
        int rb = wc * 64 + mi * 16 + lr;
        int eb = (rb << 6) + (kh << 5) + (lg << 3);
        bfr[kh][mi] = *(const bf16x8*)&Bs[eb ^ ((rb & 7) << 3)];
      }
#pragma unroll
    for (int kh = 0; kh < 2; ++kh)
#pragma unroll
      for (int mi = 0; mi < 4; ++mi)
#pragma unroll
        for (int ni = 0; ni < 4; ++ni)
          acc[mi][ni] = __builtin_amdgcn_mfma_f32_16x16x32_bf16(
              af[kh][mi], bfr[kh][ni], acc[mi][ni], 0, 0, 0);
  };

  STAGE(0, 0);
  __syncthreads();
  for (int t = 0; t < nt; ++t) {
    if (t + 1 < nt) STAGE((t + 1) & 1, t + 1);
    COMPUTE(t & 1);
    __syncthreads();
  }

#pragma unroll
  for (int ni = 0; ni < 4; ++ni) {
    int col = bn + wc * 64 + ni * 16 + lr;
    float bv = bias ? bias[col] : 0.f;
#pragma unroll
    for (int mi = 0; mi < 4; ++mi) {
#pragma unroll
      for (int j = 0; j < 4; ++j) {
        int row = bm + wr * 64 + mi * 16 + lg * 4 + j;
        float v = acc[mi][ni][j] + bv;
        if (ACT == 1) v = v > 0.f ? v : 0.2f * v;
        if (EPI == 1)
          ((unsigned short*)C)[(size_t)row * Nc + col] = cvt_bf16(v);
        else
          ((float*)C)[(size_t)row * Nc + col] = v;
      }
    }
  }
}

// ------------- bf16 MFMA GEMM 64x64 tile (2x grid for small-N GEMMs) ----------
template <int ACT, int EPI>
__global__ __launch_bounds__(256) void mgemm64_kernel(
    const unsigned short* __restrict__ A, const unsigned short* __restrict__ BT,
    const float* __restrict__ bias, void* __restrict__ C,
    int M, int Nc, int K) {
  __shared__ unsigned short lds[4][4096];
  int tid = threadIdx.x;
  int w = tid >> 6, lane = tid & 63, lg = lane >> 4, lr = lane & 15;
  int bm = blockIdx.y * 64, bn = blockIdx.x * 64;
  int wr = w >> 1, wc = w & 1;
  int segl = lane >> 3;
  int cb = (lane & 7) << 4;

  f32x4 zf = {0.f, 0.f, 0.f, 0.f};
  f32x4 acc[2][2];
#pragma unroll
  for (int mi = 0; mi < 2; ++mi)
#pragma unroll
    for (int ni = 0; ni < 2; ++ni) acc[mi][ni] = zf;

  int nt = K >> 6;

  auto STAGE = [&](int buf, int t) {
    int k0 = t << 6;
#pragma unroll
    for (int i = 0; i < 2; ++i) {
      int seg = w * 2 + i;
      int r = (seg << 3) + segl;
      int csw = cb ^ ((r & 7) << 4);
      const char* ga = (const char*)A + (((size_t)(bm + r) * K + k0) << 1) + csw;
      gl_lds16(ga, &lds[buf * 2][seg << 9]);
      const char* gb = (const char*)BT + (((size_t)(bn + r) * K + k0) << 1) + csw;
      gl_lds16(gb, &lds[buf * 2 + 1][seg << 9]);
    }
  };
  auto COMPUTE = [&](int buf) {
    const unsigned short* As = lds[buf * 2];
    const unsigned short* Bs = lds[buf * 2 + 1];
    bf16x8 af[2][2], bfr[2][2];
#pragma unroll
    for (int kh = 0; kh < 2; ++kh)
#pragma unroll
      for (int mi = 0; mi < 2; ++mi) {
        int r = wr * 32 + mi * 16 + lr;
        int e = (r << 6) + (kh << 5) + (lg << 3);
        af[kh][mi] = *(const bf16x8*)&As[e ^ ((r & 7) << 3)];
        int rb = wc * 32 + mi * 16 + lr;
        int eb = (rb << 6) + (kh << 5) + (lg << 3);
        bfr[kh][mi] = *(const bf16x8*)&Bs[eb ^ ((rb & 7) << 3)];
      }
#pragma unroll
    for (int kh = 0; kh < 2; ++kh)
#pragma unroll
      for (int mi = 0; mi < 2; ++mi)
#pragma unroll
        for (int ni = 0; ni < 2; ++ni)
          acc[mi][ni] = __builtin_amdgcn_mfma_f32_16x16x32_bf16(
              af[kh][mi], bfr[kh][ni], acc[mi][ni], 0, 0, 0);
  };

  STAGE(0, 0);
  __syncthreads();
  for (int t = 0; t < nt; ++t) {
    if (t + 1 < nt) STAGE((t + 1) & 1, t + 1);
    COMPUTE(t & 1);
    __syncthreads();
  }

#pragma unroll
  for (int ni = 0; ni < 2; ++ni) {
    int col = bn + wc * 32 + ni * 16 + lr;
    float bv = bias ? bias[col] : 0.f;
#pragma unroll
    for (int mi = 0; mi < 2; ++mi) {
#pragma unroll
      for (int j = 0; j < 4; ++j) {
        int row = bm + wr * 32 + mi * 16 + lg * 4 + j;
        float v = acc[mi][ni][j] + bv;
        if (ACT == 1) v = v > 0.f ? v : 0.2f * v;
        if (EPI == 1)
          ((unsigned short*)C)[(size_t)row * Nc + col] = cvt_bf16(v);
        else
          ((float*)C)[(size_t)row * Nc + col] = v;
      }
    }
  }
}

// ---------- fused QKV GEMM (z: 0=q norm, 1=k norm, 2=v) -> bf16 [B,H,N,64] ----
__global__ __launch_bounds__(256) void qkv_gemm_kernel(
    const unsigned short* __restrict__ q_lnb,
    const unsigned short* __restrict__ k_lnb,
    const unsigned short* __restrict__ x_bf,
    const unsigned short* __restrict__ wt,
    const float* __restrict__ bq, const float* __restrict__ bk,
    const float* __restrict__ bv_,
    unsigned short* __restrict__ q_bf, unsigned short* __restrict__ k_bf,
    unsigned short* __restrict__ v_bf) {
  int z = blockIdx.z;
  const unsigned short* A = z == 0 ? q_lnb : z == 1 ? k_lnb : x_bf;
  const unsigned short* BT = wt + (size_t)z * 262144;
  const float* bias = z == 0 ? bq : z == 1 ? bk : bv_;

  __shared__ unsigned short lds[4][8192];
  int tid = threadIdx.x;
  int w = tid >> 6, lane = tid & 63, lg = lane >> 4, lr = lane & 15;
  int bm = blockIdx.y * 128, bn = blockIdx.x * 128;
  int wr = w >> 1, wc = w & 1;
  int segl = lane >> 3;
  int cb = (lane & 7) << 4;

  f32x4 zf = {0.f, 0.f, 0.f, 0.f};
  f32x4 acc[4][4];
#pragma unroll
  for (int mi = 0; mi < 4; ++mi)
#pragma unroll
    for (int ni = 0; ni < 4; ++ni) acc[mi][ni] = zf;

  auto STAGE = [&](int buf, int t) {
    int k0 = t << 6;
#pragma unroll
    for (int i = 0; i < 4; ++i) {
      int seg = w * 4 + i;
      int r = (seg << 3) + segl;
      int csw = cb ^ ((r & 7) << 4);
      const char* ga = (const char*)A + (((size_t)(bm + r) * DD + k0) << 1) + csw;
      gl_lds16(ga, &lds[buf * 2][seg << 9]);
      const char* gb = (const char*)BT + (((size_t)(bn + r) * DD + k0) << 1) + csw;
      gl_lds16(gb, &lds[buf * 2 + 1][seg << 9]);
    }
  };
  auto COMPUTE = [&](int buf) {
    const unsigned short* As = lds[buf * 2];
    const unsigned short* Bs = lds[buf * 2 + 1];
    bf16x8 af[2][4], bfr[2][4];
#pragma unroll
    for (int kh = 0; kh < 2; ++kh)
#pragma unroll
      for (int mi = 0; mi < 4; ++mi) {
        int r = wr * 64 + mi * 16 + lr;
        int e = (r << 6) + (kh << 5) + (lg << 3);
        af[kh][mi] = *(const bf16x8*)&As[e ^ ((r & 7) << 3)];
        int rb = wc * 64 + mi * 16 + lr;
        int eb = (rb << 6) + (kh << 5) + (lg << 3);
        bfr[kh][mi] = *(const bf16x8*)&Bs[eb ^ ((rb & 7) << 3)];
      }
#pragma unroll
    for (int kh = 0; kh < 2; ++kh)
#pragma unroll
      for (int mi = 0; mi < 4; ++mi)
#pragma unroll
        for (int ni = 0; ni < 4; ++ni)
          acc[mi][ni] = __builtin_amdgcn_mfma_f32_16x16x32_bf16(
              af[kh][mi], bfr[kh][ni], acc[mi][ni], 0, 0, 0);
  };

  STAGE(0, 0);
  __syncthreads();
  for (int t = 0; t < 8; ++t) {
    if (t + 1 < 8) STAGE((t + 1) & 1, t + 1);
    COMPUTE(t & 1);
    __syncthreads();
  }

  int h = (bn >> 6) + wc;   // wave's 64-col block == one head
  float bvf[4];
#pragma unroll
  for (int ni = 0; ni < 4; ++ni) bvf[ni] = bias[bn + wc * 64 + ni * 16 + lr];
#pragma unroll
  for (int mi = 0; mi < 4; ++mi) {
#pragma unroll
    for (int j = 0; j < 4; ++j) {
      float vals[4]; float ss = 0.f;
#pragma unroll
      for (int ni = 0; ni < 4; ++ni) {
        float v = acc[mi][ni][j] + bvf[ni];
        vals[ni] = v;
        ss = fmaf(v, v, ss);
      }
      float rn = 1.f;
      if (z <= 1) {
        ss += __shfl_xor(ss, 1);
        ss += __shfl_xor(ss, 2);
        ss += __shfl_xor(ss, 4);
        ss += __shfl_xor(ss, 8);
        rn = 1.f / fmaxf(sqrtf(ss), 1e-12f);
      }
      int row = bm + wr * 64 + mi * 16 + lg * 4 + j;
      int b_ = row >> 10, n_ = row & (NN - 1);
      unsigned short* ob = (z == 0 ? q_bf : z == 1 ? k_bf : v_bf) +
                           (((size_t)b_ * HH + h) * NN + n_) * DHH;
#pragma unroll
      for (int ni = 0; ni < 4; ++ni)
        ob[ni * 16 + lr] = cvt_bf16(vals[ni] * rn);
    }
  }
}

// ---- MFMA flash attention, V fully LDS-resident, barrier-free main loop ------
// NT = k-tiles per block (NSPLIT = 16/NT = 4). One barrier total (after V stage).
__global__ __launch_bounds__(256) void attn_vres_kernel(
    const unsigned short* __restrict__ qb, const unsigned short* __restrict__ kb,
    const unsigned short* __restrict__ vb,
    const unsigned short* __restrict__ bias_g,
    const float* __restrict__ logit_scale,
    unsigned short* __restrict__ part, int nb) {
  const int NT = 4;
  int qt = blockIdx.x, h = blockIdx.y;
  int b = blockIdx.z % nb, sp = blockIdx.z / nb;
  int tid = threadIdx.x;
  int w = tid >> 6, lane = tid & 63;
  int lg = lane >> 4, lr = lane & 15;

  __shared__ unsigned short vt[NT * 4096];  // all block's V^T tiles, swizzled
  __shared__ unsigned short pl[4][1024];    // per-wave P, swizzled

  const size_t bh = ((size_t)b * HH + h) * NN;
  const int kt0 = sp * NT;

  int q_glob = qt * 64 + w * 16 + lr;
  bf16x8 aq0 = *(const bf16x8*)&qb[(bh + q_glob) * DHH + lg * 8];
  bf16x8 aq1 = *(const bf16x8*)&qb[(bh + q_glob) * DHH + 32 + lg * 8];

  const unsigned short* brow[4];
#pragma unroll
  for (int r = 0; r < 4; ++r) {
    int qg = qt * 64 + w * 16 + lg * 4 + r;
    brow[r] = &bias_g[(bh + qg) * NN + lr];
  }
  float scale_h = __expf(fminf(logit_scale[h], 4.605170185988091f));

  float m_run[4] = {-1e30f, -1e30f, -1e30f, -1e30f};
  float l_run[4] = {0.f, 0.f, 0.f, 0.f};
  f32x4 zf = {0.f, 0.f, 0.f, 0.f};
  f32x4 acc_o[4] = {zf, zf, zf, zf};

  // prologue: stage ALL NT V-tiles (transposed+swizzled), one barrier
#pragma unroll
  for (int t = 0; t < NT; ++t) {
#pragma unroll
    for (int it = 0; it < 2; ++it) {
      int kl = it * 32 + (tid & 31);
      int d0 = (tid >> 5) * 8;
      bf16x8 vv = *(const bf16x8*)&vb[(bh + (kt0 + t) * 64 + kl) * DHH + d0];
#pragma unroll
      for (int j = 0; j < 8; ++j) {
        int d = d0 + j;
        vt[t * 4096 + ((d * 64 + kl) ^ ((d & 7) << 3))] = (unsigned short)vv[j];
      }
    }
  }
  // bias tile-0 prefetch (before the barrier so it overlaps)
  unsigned short bu[4][4];
#pragma unroll
  for (int r = 0; r < 4; ++r)
#pragma unroll
    for (int kc = 0; kc < 4; ++kc) bu[kc][r] = brow[r][kt0 * 64 + kc * 16];
  __syncthreads();

  // barrier-free main loop: compiler can pipeline across tiles
  for (int t = 0; t < NT; ++t) {
    int ktg = kt0 + t;

    f32x4 s_acc[4];
#pragma unroll
    for (int kc = 0; kc < 4; ++kc) {
      const unsigned short* krow =
          &kb[(bh + ktg * 64 + kc * 16 + lr) * DHH + lg * 8];
      bf16x8 bk0 = *(const bf16x8*)krow;
      bf16x8 bk1 = *(const bf16x8*)(krow + 32);
      s_acc[kc] = __builtin_amdgcn_mfma_f32_16x16x32_bf16(aq0, bk0, zf, 0, 0, 0);
      s_acc[kc] = __builtin_amdgcn_mfma_f32_16x16x32_bf16(aq1, bk1, s_acc[kc], 0, 0, 0);
    }

#pragma unroll
    for (int kc = 0; kc < 4; ++kc)
#pragma unroll
      for (int r = 0; r < 4; ++r) {
        float bf_ = __uint_as_float(((unsigned)bu[kc][r]) << 16);
        s_acc[kc][r] = fmaf(s_acc[kc][r], scale_h, bf_);
      }

    // next tile's bias prefetch (no barrier ahead -> never drained)
    unsigned short bu2[4][4];
    if (t + 1 < NT) {
#pragma unroll
      for (int r = 0; r < 4; ++r)
#pragma unroll
        for (int kc = 0; kc < 4; ++kc)
          bu2[kc][r] = brow[r][(ktg + 1) * 64 + kc * 16];
    }

    float pf[4][4];
#pragma unroll
    for (int r = 0; r < 4; ++r) {
      float mx = fmaxf(fmaxf(s_acc[0][r], s_acc[1][r]),
                       fmaxf(s_acc[2][r], s_acc[3][r]));
      mx = fmaxf(mx, __shfl_xor(mx, 1));
      mx = fmaxf(mx, __shfl_xor(mx, 2));
      mx = fmaxf(mx, __shfl_xor(mx, 4));
      mx = fmaxf(mx, __shfl_xor(mx, 8));
      float m_new = fmaxf(m_run[r], mx);
      float alpha = __expf(m_run[r] - m_new);
      m_run[r] = m_new;
      float ps = 0.f;
#pragma unroll
      for (int kc = 0; kc < 4; ++kc) {
        float p = __expf(s_acc[kc][r] - m_new);
        pf[kc][r] = p;
        ps += p;
      }
      l_run[r] = l_run[r] * alpha + ps;
#pragma unroll
      for (int ds = 0; ds < 4; ++ds) acc_o[ds][r] *= alpha;
    }

    // P -> per-wave LDS (wave-local; lgkmcnt ordering only)
#pragma unroll
    for (int kc = 0; kc < 4; ++kc)
#pragma unroll
      for (int r = 0; r < 4; ++r) {
        int q = lg * 4 + r;
        pl[w][(q * 64 + kc * 16 + lr) ^ ((q & 7) << 3)] = cvt_bf16(pf[kc][r]);
      }

    // O += P @ V (V resident in LDS)
#pragma unroll
    for (int ka = 0; ka < 2; ++ka) {
      bf16x8 pa = *(const bf16x8*)&pl[w][(lr * 64 + ka * 32 + lg * 8) ^
                                         ((lr & 7) << 3)];
#pragma unroll
      for (int ds = 0; ds < 4; ++ds) {
        int d = ds * 16 + lr;
        bf16x8 bv = *(const bf16x8*)&vt[t * 4096 +
            ((d * 64 + ka * 32 + lg * 8) ^ ((d & 7) << 3))];
        acc_o[ds] = __builtin_amdgcn_mfma_f32_16x16x32_bf16(pa, bv, acc_o[ds], 0, 0, 0);
      }
    }

    if (t + 1 < NT) {
#pragma unroll
      for (int r = 0; r < 4; ++r)
#pragma unroll
        for (int kc = 0; kc < 4; ++kc) bu[kc][r] = bu2[kc][r];
    }
  }

#pragma unroll
  for (int r = 0; r < 4; ++r) {
    l_run[r] += __shfl_xor(l_run[r], 1);
    l_run[r] += __shfl_xor(l_run[r], 2);
    l_run[r] += __shfl_xor(l_run[r], 4);
    l_run[r] += __shfl_xor(l_run[r], 8);
  }

#pragma unroll
  for (int r = 0; r < 4; ++r) {
    int qg = qt * 64 + w * 16 + lg * 4 + r;
    size_t idx = ((size_t)(sp * nb + b) * HH + h) * NN + qg;
    unsigned short* pr = part + idx * 68;
#pragma unroll
    for (int ds = 0; ds < 4; ++ds)
      pr[ds * 16 + lr] = cvt_bf16(acc_o[ds][r]);
    if (lr == 0) {
      *(float*)(pr + 64) = m_run[r];
      *(float*)(pr + 66) = l_run[r];
    }
  }
}

// ---- fallback attention (r9 structure, NSPLIT=1, direct write) ---------------
__global__ __launch_bounds__(256) void attn_kernel1(
    const unsigned short* __restrict__ qb, const unsigned short* __restrict__ kb,
    const unsigned short* __restrict__ vb,
    const unsigned short* __restrict__ bias_g,
    const float* __restrict__ logit_scale,
    unsigned short* __restrict__ attb) {
  int qt = blockIdx.x, h = blockIdx.y, b = blockIdx.z;
  int tid = threadIdx.x;
  int w = tid >> 6, lane = tid & 63;
  int lg = lane >> 4, lr = lane & 15;

  __shared__ unsigned short vt[64 * 64];
  __shared__ unsigned short pl[4][1024];

  const size_t bh = ((size_t)b * HH + h) * NN;

  int q_glob = qt * 64 + w * 16 + lr;
  bf16x8 aq0 = *(const bf16x8*)&qb[(bh + q_glob) * DHH + lg * 8];
  bf16x8 aq1 = *(const bf16x8*)&qb[(bh + q_glob) * DHH + 32 + lg * 8];

  const unsigned short* brow[4];
#pragma unroll
  for (int r = 0; r < 4; ++r) {
    int qg = qt * 64 + w * 16 + lg * 4 + r;
    brow[r] = &bias_g[(bh + qg) * NN + lr];
  }
  float scale_h = __expf(fminf(logit_scale[h], 4.605170185988091f));

  float m_run[4] = {-1e30f, -1e30f, -1e30f, -1e30f};
  float l_run[4] = {0.f, 0.f, 0.f, 0.f};
  f32x4 zf = {0.f, 0.f, 0.f, 0.f};
  f32x4 acc_o[4] = {zf, zf, zf, zf};

  unsigned short bu[4][4];
#pragma unroll
  for (int r = 0; r < 4; ++r)
#pragma unroll
    for (int kc = 0; kc < 4; ++kc) bu[kc][r] = brow[r][kc * 16];

  for (int t = 0; t < 16; ++t) {
    __syncthreads();
#pragma unroll
    for (int it = 0; it < 2; ++it) {
      int kl = it * 32 + (tid & 31);
      int d0 = (tid >> 5) * 8;
      bf16x8 vv = *(const bf16x8*)&vb[(bh + t * 64 + kl) * DHH + d0];
#pragma unroll
      for (int j = 0; j < 8; ++j) {
        int d = d0 + j;
        vt[(d * 64 + kl) ^ ((d & 7) << 3)] = (unsigned short)vv[j];
      }
    }
    __syncthreads();

    f32x4 s_acc[4];
#pragma unroll
    for (int kc = 0; kc < 4; ++kc) {
      const unsigned short* krow =
          &kb[(bh + t * 64 + kc * 16 + lr) * DHH + lg * 8];
      bf16x8 bk0 = *(const bf16x8*)krow;
      bf16x8 bk1 = *(const bf16x8*)(krow + 32);
      s_acc[kc] = __builtin_amdgcn_mfma_f32_16x16x32_bf16(aq0, bk0, zf, 0, 0, 0);
      s_acc[kc] = __builtin_amdgcn_mfma_f32_16x16x32_bf16(aq1, bk1, s_acc[kc], 0, 0, 0);
    }

#pragma unroll
    for (int kc = 0; kc < 4; ++kc)
#pragma unroll
      for (int r = 0; r < 4; ++r) {
        float bf_ = __uint_as_float(((unsigned)bu[kc][r]) << 16);
        s_acc[kc][r] = fmaf(s_acc[kc][r], scale_h, bf_);
      }

    unsigned short bu2[4][4];
    if (t + 1 < 16) {
#pragma unroll
      for (int r = 0; r < 4; ++r)
#pragma unroll
        for (int kc = 0; kc < 4; ++kc)
          bu2[kc][r] = brow[r][(t + 1) * 64 + kc * 16];
    }

    float pf[4][4];
#pragma unroll
    for (int r = 0; r < 4; ++r) {
      float mx = fmaxf(fmaxf(s_acc[0][r], s_acc[1][r]),
                       fmaxf(s_acc[2][r], s_acc[3][r]));
      mx = fmaxf(mx, __shfl_xor(mx, 1));
      mx = fmaxf(mx, __shfl_xor(mx, 2));
      mx = fmaxf(mx, __shfl_xor(mx, 4));
      mx = fmaxf(mx, __shfl_xor(mx, 8));
      float m_new = fmaxf(m_run[r], mx);
      float alpha = __expf(m_run[r] - m_new);
      m_run[r] = m_new;
      float ps = 0.f;
#pragma unroll
      for (int kc = 0; kc < 4; ++kc) {
        float p = __expf(s_acc[kc][r] - m_new);
        pf[kc][r] = p;
        ps += p;
      }
      l_run[r] = l_run[r] * alpha + ps;
#pragma unroll
      for (int ds = 0; ds < 4; ++ds) acc_o[ds][r] *= alpha;
    }

#pragma unroll
    for (int kc = 0; kc < 4; ++kc)
#pragma unroll
      for (int r = 0; r < 4; ++r) {
        int q = lg * 4 + r;
        pl[w][(q * 64 + kc * 16 + lr) ^ ((q & 7) << 3)] = cvt_bf16(pf[kc][r]);
      }

#pragma unroll
    for (int ka = 0; ka < 2; ++ka) {
      bf16x8 pa = *(const bf16x8*)&pl[w][(lr * 64 + ka * 32 + lg * 8) ^
                                         ((lr & 7) << 3)];
#pragma unroll
      for (int ds = 0; ds < 4; ++ds) {
        int d = ds * 16 + lr;
        bf16x8 bv = *(const bf16x8*)&vt[(d * 64 + ka * 32 + lg * 8) ^ ((d & 7) << 3)];
        acc_o[ds] = __builtin_amdgcn_mfma_f32_16x16x32_bf16(pa, bv, acc_o[ds], 0, 0, 0);
      }
    }

    if (t + 1 < 16) {
#pragma unroll
      for (int r = 0; r < 4; ++r)
#pragma unroll
        for (int kc = 0; kc < 4; ++kc) bu[kc][r] = bu2[kc][r];
    }
  }

#pragma unroll
  for (int r = 0; r < 4; ++r) {
    l_run[r] += __shfl_xor(l_run[r], 1);
    l_run[r] += __shfl_xor(l_run[r], 2);
    l_run[r] += __shfl_xor(l_run[r], 4);
    l_run[r] += __shfl_xor(l_run[r], 8);
  }
#pragma unroll
  for (int ds = 0; ds < 4; ++ds)
#pragma unroll
    for (int r = 0; r < 4; ++r) {
      int qg = qt * 64 + w * 16 + lg * 4 + r;
      attb[((size_t)b * NN + qg) * DD + h * DHH + ds * 16 + lr] =
          cvt_bf16(acc_o[ds][r] / l_run[r]);
    }
}

// ---------------- combine NS k-split partials -> att bf16 ---------------------
template <int NS>
__global__ __launch_bounds__(256) void combine_kernel(
    const unsigned short* __restrict__ part, unsigned short* __restrict__ attb,
    int nb) {
  int tid = threadIdx.x;
  int w = tid >> 6, d = tid & 63;
  int row = blockIdx.x * 4 + w;
  int b = row >> 13, rem = row & 8191, h = rem >> 10, n = rem & (NN - 1);
  size_t i0 = ((size_t)b * HH + h) * NN + n;
  size_t stride = (size_t)nb * HH * NN;
  float m[NS], l[NS], a[NS];
#pragma unroll
  for (int s = 0; s < NS; ++s) {
    const unsigned short* p = part + (i0 + s * stride) * 68;
    m[s] = *(const float*)(p + 64);
    l[s] = *(const float*)(p + 66);
    a[s] = __uint_as_float(((unsigned)p[d]) << 16);
  }
  float ms = m[0];
#pragma unroll
  for (int s = 1; s < NS; ++s) ms = fmaxf(ms, m[s]);
  float num = 0.f, den = 0.f;
#pragma unroll
  for (int s = 0; s < NS; ++s) {
    float wgt = __expf(m[s] - ms);
    num = fmaf(a[s], wgt, num);
    den = fmaf(l[s], wgt, den);
  }
  attb[((size_t)b * NN + n) * DD + h * DHH + d] = cvt_bf16(num / den);
}

// ---------------- launcher ----------------
extern "C" void kernel_launch(void* const* d_in, const int* in_sizes, int n_in,
                              void* d_out, int out_size, void* d_ws, size_t ws_size,
                              hipStream_t stream) {
  const float* x      = (const float*)d_in[0];
  const float* coords = (const float*)d_in[1];
  const float* Wq = (const float*)d_in[2];  const float* bq = (const float*)d_in[3];
  const float* Wk = (const float*)d_in[4];  const float* bk = (const float*)d_in[5];
  const float* Wv = (const float*)d_in[6];  const float* bv = (const float*)d_in[7];
  const float* Wo = (const float*)d_in[8];  const float* bo = (const float*)d_in[9];
  const float* logit_scale = (const float*)d_in[10];
  const float* W_pe = (const float*)d_in[11]; const float* b_pe = (const float*)d_in[12];
  const float* W_r1 = (const float*)d_in[13]; const float* b_r1 = (const float*)d_in[14];
  const float* W_r2 = (const float*)d_in[15]; const float* b_r2 = (const float*)d_in[16];
  const float* g_peq = (const float*)d_in[17]; const float* bt_peq = (const float*)d_in[18];
  const float* g_pek = (const float*)d_in[19]; const float* bt_pek = (const float*)d_in[20];
  const float* g2 = (const float*)d_in[21]; const float* bt2 = (const float*)d_in[22];
  const float* g3 = (const float*)d_in[23]; const float* bt3 = (const float*)d_in[24];
  const float* W_ff1 = (const float*)d_in[25];
  const float* W_ff2 = (const float*)d_in[26];
  float* out = (float*)d_out;

  const size_t T = (size_t)BB * NN;
  char* wsb = (char*)d_ws;
  const size_t U = 4u * 1024u * 1024u;

  unsigned short* wt_all = (unsigned short*)(wsb + 0 * U);   // [0,2U)
  unsigned short* WoT   = wt_all + 786432;
  unsigned short* Wff1T = wt_all + 1048576;
  unsigned short* Wff2T = wt_all + 2097152;
  unsigned short* q_lnb = (unsigned short*)(wsb + 2 * U);
  unsigned short* k_lnb = (unsigned short*)(wsb + 3 * U);
  unsigned short* x_bf  = (unsigned short*)(wsb + 4 * U);
  unsigned short* q_bf  = (unsigned short*)(wsb + 5 * U);
  unsigned short* k_bf  = (unsigned short*)(wsb + 6 * U);
  unsigned short* v_bf  = (unsigned short*)(wsb + 7 * U);    // [B,H,N,64]
  unsigned short* att_bf = (unsigned short*)(wsb + 8 * U);
  float* proj = (float*)(wsb + 9 * U);                        // [9U,11U)
  float* x1   = (float*)(wsb + 11 * U);                       // [11U,13U)
  unsigned short* x1_bf = (unsigned short*)(wsb + 13 * U);    // [13U,14U)
  unsigned short* hid_bf = (unsigned short*)(wsb + 2 * U);    // [2U,6U)
  float* mlp  = (float*)(wsb + 9 * U);
  // attention-phase overlays:
  unsigned short* bias_ws = (unsigned short*)(wsb + 9 * U);   // 64 MiB [9U,25U)
  unsigned short* part4_ws = (unsigned short*)(wsb + 25 * U); // 17.8 MiB

  wconv_kernel<<<dim3(768), dim3(256), 0, stream>>>(
      Wq, Wk, Wv, Wo, W_ff1, W_ff2, wt_all);

  pe_ln_kernel<<<dim3(T / 4), dim3(512), 0, stream>>>(
      x, coords, W_pe, b_pe, g_peq, bt_peq, g_pek, bt_pek, q_lnb, k_lnb, x_bf);

  qkv_gemm_kernel<<<dim3(DD / 128, T / 128, 3), dim3(256), 0, stream>>>(
      q_lnb, k_lnb, x_bf, wt_all, bq, bk, bv, q_bf, k_bf, v_bf);

  if (ws_size >= 30 * U) {
    bias_kernel<<<dim3(NN / 32, NN / 64, BB), dim3(256), 0, stream>>>(
        coords, W_r1, b_r1, W_r2, b_r2, bias_ws);
    attn_vres_kernel<<<dim3(NN / 64, HH, 4 * BB), dim3(256), 0, stream>>>(
        q_bf, k_bf, v_bf, bias_ws, logit_scale, part4_ws, BB);
    combine_kernel<4><<<dim3(BB * HH * NN / 4), dim3(256), 0, stream>>>(
        part4_ws, att_bf, BB);
  } else {
    // per-batch fallback: 16 MiB bias in [9U,13U)
    for (int b = 0; b < BB; ++b) {
      bias_kernel<<<dim3(NN / 32, NN / 64, 1), dim3(256), 0, stream>>>(
          coords + (size_t)b * NN * 2, W_r1, b_r1, W_r2, b_r2, bias_ws);
      attn_kernel1<<<dim3(NN / 64, HH, 1), dim3(256), 0, stream>>>(
          q_bf + (size_t)b * HH * NN * DHH, k_bf + (size_t)b * HH * NN * DHH,
          v_bf + (size_t)b * HH * NN * DHH, bias_ws, logit_scale,
          att_bf + (size_t)b * NN * DD);
    }
  }

  mgemm64_kernel<0, 0><<<dim3(DD / 64, T / 64), dim3(256), 0, stream>>>(
      att_bf, WoT, bo, proj, (int)T, DD, DD);

  add_ln_kernel<<<dim3(T / 4), dim3(512), 0, stream>>>(
      x, proj, g2, bt2, x1, x1_bf);

  mgemm_kernel<1, 1><<<dim3(FFF / 128, T / 128), dim3(256), 0, stream>>>(
      x1_bf, Wff1T, nullptr, hid_bf, (int)T, FFF, DD);
  mgemm64_kernel<1, 0><<<dim3(DD / 64, T / 64), dim3(256), 0, stream>>>(
      hid_bf, Wff2T, nullptr, mlp, (int)T, DD, FFF);

  add_ln_kernel<<<dim3(T / 4), dim3(512), 0, stream>>>(
      x1, mlp, g3, bt3, out, nullptr);
}